// Round 5
// baseline (73.638 us; speedup 1.0000x reference)
//
#include <hip/hip_runtime.h>

#define BATCH 8
#define NPRED 25200
#define NCLS 80
#define ROWW 85
#define TOPKK 2048
#define MAXDET 300
#define CANDMAX 4096
#define NBUCKET 4096
#define CONF_T 0.2f
#define IOU_T 0.6f
#define CLS_OFF 4096.0f

#define MASKN 384              // candidates with precomputed masks
#define MCH (MASKN / 64)       // 6 chunks
#define MW 13                  // u32 stride per mask row (gcd(13,32)=1: conflict-free)

__device__ __forceinline__ int bucket_of_key(unsigned long long k) {
    float sc = __uint_as_float((unsigned)(k >> 32));
    int bkt = (int)(sc * (float)NBUCKET);
    return (bkt > NBUCKET - 1) ? (NBUCKET - 1) : bkt;
}

// ---------------- K1: LDS-staged score/key, tree argmax ----------------
__global__ __launch_bounds__(64) void k_score(
    const float* __restrict__ preds,
    unsigned long long* __restrict__ keys,
    unsigned char* __restrict__ cls8)
{
    __shared__ float rows[64 * ROWW];   // 21760 B
    const int lane = threadIdx.x;
    const size_t rowbase = (size_t)blockIdx.x * 64;

    const float4* src = reinterpret_cast<const float4*>(preds + rowbase * ROWW);
    float4* dst = reinterpret_cast<float4*>(rows);
    #pragma unroll
    for (int i = lane; i < 64 * ROWW / 4; i += 64) dst[i] = src[i];
    __syncthreads();

    const float* p = rows + lane * ROWW;
    float obj = p[4];

    // 8 parallel accumulators; exact first-index-on-tie semantics.
    float bs[8];
    int bi[8];
    #pragma unroll
    for (int k = 0; k < 8; ++k) {
        bs[k] = __fmul_rn(obj, p[5 + k]);
        bi[k] = k;
    }
    #pragma unroll
    for (int c = 8; c < NCLS; c += 8) {
        #pragma unroll
        for (int k = 0; k < 8; ++k) {
            float s = __fmul_rn(obj, p[5 + c + k]);
            if (s > bs[k]) { bs[k] = s; bi[k] = c + k; }  // first occurrence wins
        }
    }
    #pragma unroll
    for (int off = 4; off >= 1; off >>= 1) {
        #pragma unroll
        for (int k = 0; k < off; ++k) {
            bool take = (bs[k + off] > bs[k]) ||
                        ((bs[k + off] == bs[k]) && (bi[k + off] < bi[k]));
            if (take) { bs[k] = bs[k + off]; bi[k] = bi[k + off]; }
        }
    }
    float best = bs[0];
    int bc = bi[0];

    size_t gid = rowbase + lane;
    unsigned long long key = 0ull;
    if (best > CONF_T) {
        unsigned fb = __float_as_uint(best);
        unsigned i = (unsigned)(gid % NPRED);
        key = ((unsigned long long)fb << 32) | (0xFFFFFFFFu - i);
    }
    keys[gid] = key;
    cls8[gid] = (unsigned char)bc;
}

// ---------------- K2: fused top-2048 select + mask-matrix NMS ----------------
struct SelPhase {
    unsigned int hist[NBUCKET];          // 16 KB
    unsigned int bstart[NBUCKET];        // 16 KB
    unsigned int bfill[NBUCKET];         // 16 KB
    unsigned long long cand[CANDMAX];    // 32 KB
    unsigned int partial[1024];          // 4 KB
};
struct NmsPhase {
    unsigned int masks32[MASKN * MW];    // 19968 B (upper-triangle masks)
    float4 cbx[MASKN];                   // offset boxes
    float carea[MASKN];
    float4 kb[MAXDET];                   // kept offset boxes
};

__global__ __launch_bounds__(1024) void k_fused(
    const float* __restrict__ preds,
    const unsigned long long* __restrict__ keys,
    const unsigned char* __restrict__ cls8,
    float* __restrict__ cbox,
    float* __restrict__ cscore,
    float* __restrict__ ccls,
    float* __restrict__ out)
{
    __shared__ union { SelPhase sel; NmsPhase nms; } u;   // 84 KB
    __shared__ float4 sbox[MASKN];                        // 6 KB (original boxes)
    __shared__ float sscore[MASKN];                       // 1.5 KB
    __shared__ float scls[MASKN];                         // 1.5 KB
    __shared__ unsigned long long validw[MCH];
    __shared__ int s_tb;
    __shared__ unsigned int s_stored;

    const int b = blockIdx.x;
    const int t = threadIdx.x;
    const int lane = t & 63;
    const int wave = t >> 6;
    const unsigned long long* bk = keys + (size_t)b * NPRED;
    float* ob = out + (size_t)b * MAXDET * 6;

    // ================= SELECT PHASE =================
    for (int i = t; i < NBUCKET; i += 1024) { u.sel.hist[i] = 0u; u.sel.bfill[i] = 0u; }
    if (t == 0) s_tb = 0;
    __syncthreads();

    for (int i = t; i < NPRED; i += 1024) {
        unsigned long long k = bk[i];
        if (k) atomicAdd(&u.sel.hist[bucket_of_key(k)], 1u);
    }
    __syncthreads();

    unsigned h0 = u.sel.hist[4 * t], h1 = u.sel.hist[4 * t + 1];
    unsigned h2 = u.sel.hist[4 * t + 2], h3 = u.sel.hist[4 * t + 3];
    u.sel.partial[t] = h0 + h1 + h2 + h3;
    __syncthreads();
    for (int off = 1; off < 1024; off <<= 1) {
        unsigned int v = u.sel.partial[t] + ((t + off < 1024) ? u.sel.partial[t + off] : 0u);
        __syncthreads();
        u.sel.partial[t] = v;
        __syncthreads();
    }

    unsigned snext = (t < 1023) ? u.sel.partial[t + 1] : 0u;
    unsigned b3 = snext;
    unsigned b2 = b3 + h3;
    unsigned b1 = b2 + h2;
    unsigned b0 = b1 + h1;
    u.sel.bstart[4 * t + 3] = b3;
    u.sel.bstart[4 * t + 2] = b2;
    u.sel.bstart[4 * t + 1] = b1;
    u.sel.bstart[4 * t + 0] = b0;
    {
        unsigned cnt3 = b3 + h3, cnt2 = b2 + h2, cnt1 = b1 + h1, cnt0 = b0 + h0;
        if (cnt3 >= TOPKK && b3 < TOPKK) s_tb = 4 * t + 3;
        if (cnt2 >= TOPKK && b2 < TOPKK) s_tb = 4 * t + 2;
        if (cnt1 >= TOPKK && b1 < TOPKK) s_tb = 4 * t + 1;
        if (cnt0 >= TOPKK && b0 < TOPKK) s_tb = 4 * t + 0;
    }
    __syncthreads();
    const int tb = s_tb;
    if (t == 0) {
        unsigned cnt = u.sel.bstart[tb] + u.sel.hist[tb];
        s_stored = (cnt < (unsigned)CANDMAX) ? cnt : (unsigned)CANDMAX;
    }

    for (int i = t; i < NPRED; i += 1024) {
        unsigned long long k = bk[i];
        if (k) {
            int bkt = bucket_of_key(k);
            if (bkt >= tb) {
                unsigned slot = u.sel.bstart[bkt] + atomicAdd(&u.sel.bfill[bkt], 1u);
                if (slot < CANDMAX) u.sel.cand[slot] = k;
            }
        }
    }
    __syncthreads();
    const unsigned stored = s_stored;

    // zero-fill unwritten ranks (LDS < MASKN, global >= MASKN)
    for (unsigned i = stored + t; i < TOPKK; i += 1024) {
        if (i < MASKN) {
            sbox[i] = make_float4(0.f, 0.f, 0.f, 0.f);
            sscore[i] = 0.f;
            scls[i] = 0.f;
        } else {
            size_t o = (size_t)b * TOPKK + i;
            cbox[o * 4 + 0] = 0.f; cbox[o * 4 + 1] = 0.f;
            cbox[o * 4 + 2] = 0.f; cbox[o * 4 + 3] = 0.f;
            cscore[o] = 0.f; ccls[o] = 0.f;
        }
    }

    // exact rank + emit (LDS for rank<MASKN, global otherwise)
    for (unsigned i = t; i < stored; i += 1024) {
        unsigned long long k = u.sel.cand[i];
        int bkt = bucket_of_key(k);
        unsigned base = u.sel.bstart[bkt];
        unsigned end = base + u.sel.hist[bkt];
        if (end > stored) end = stored;
        unsigned r = base;
        for (unsigned j = base; j < end; ++j) r += (u.sel.cand[j] > k) ? 1u : 0u;
        if (r < TOPKK) {
            float sc = __uint_as_float((unsigned)(k >> 32));
            unsigned idx = 0xFFFFFFFFu - (unsigned)(k & 0xFFFFFFFFu);
            const float* p = preds + ((size_t)b * NPRED + idx) * ROWW;
            float cx = p[0], cy = p[1], w = p[2], h = p[3];
            float hw = __fmul_rn(w, 0.5f);
            float hh = __fmul_rn(h, 0.5f);
            float x1 = __fsub_rn(cx, hw);
            float y1 = __fsub_rn(cy, hh);
            float x2 = __fadd_rn(cx, hw);
            float y2 = __fadd_rn(cy, hh);
            float cl = (float)cls8[(size_t)b * NPRED + idx];
            if (r < MASKN) {
                sbox[r] = make_float4(x1, y1, x2, y2);
                sscore[r] = sc;
                scls[r] = cl;
            } else {
                size_t o = (size_t)b * TOPKK + r;
                cbox[o * 4 + 0] = x1; cbox[o * 4 + 1] = y1;
                cbox[o * 4 + 2] = x2; cbox[o * 4 + 3] = y2;
                cscore[o] = sc; ccls[o] = cl;
            }
        }
    }
    __syncthreads();   // select LDS dead; switch union to NMS phase

    // ================= NMS PHASE =================
    // phase 1: offset boxes, areas, valid bits
    if (t < MASKN) {
        float sc = sscore[t];
        float cl = scls[t];
        float4 bb = sbox[t];
        float off = __fmul_rn(cl, CLS_OFF);
        float4 obx = make_float4(__fadd_rn(bb.x, off), __fadd_rn(bb.y, off),
                                 __fadd_rn(bb.z, off), __fadd_rn(bb.w, off));
        u.nms.cbx[t] = obx;
        u.nms.carea[t] = __fmul_rn(__fsub_rn(obx.z, obx.x), __fsub_rn(obx.w, obx.y));
        unsigned long long vb = __ballot(sc > CONF_T);
        if (lane == 0) validw[wave] = vb;
    }
    __syncthreads();

    // phase 2: upper-triangle masks. 42 (q, 32-col-slice s) units with s>=2q,
    // distributed over 16 waves (<=3 units each).
    for (int tu = 0; tu < 3; ++tu) {
        int uidx = wave + 16 * tu;
        if (uidx >= 42) break;
        int q, s;
        if (uidx < 12)      { q = 0; s = uidx; }
        else if (uidx < 22) { q = 1; s = uidx - 12 + 2; }
        else if (uidx < 30) { q = 2; s = uidx - 22 + 4; }
        else if (uidx < 36) { q = 3; s = uidx - 30 + 6; }
        else if (uidx < 40) { q = 4; s = uidx - 36 + 8; }
        else                { q = 5; s = uidx - 40 + 10; }

        const int r = q * 64 + lane;
        const float4 me = u.nms.cbx[r];
        const float aA = u.nms.carea[r];
        const int j0 = s * 32;
        unsigned acc = 0u;
        #pragma unroll 8
        for (int jj = 0; jj < 32; ++jj) {
            const int j = j0 + jj;
            float4 cb = u.nms.cbx[j];
            float lx = fmaxf(me.x, cb.x), ly = fmaxf(me.y, cb.y);
            float rx = fminf(me.z, cb.z), ry = fminf(me.w, cb.w);
            float iw = fmaxf(__fsub_rn(rx, lx), 0.0f);
            float ih = fmaxf(__fsub_rn(ry, ly), 0.0f);
            float inter = __fmul_rn(iw, ih);
            float denom = __fadd_rn(__fsub_rn(__fadd_rn(aA, u.nms.carea[j]), inter), 1e-9f);
            bool sv = inter > __fmul_rn(IOU_T, denom);
            acc |= ((unsigned)sv) << jj;
        }
        if (s == 2 * q || s == 2 * q + 1) {     // diagonal slice: keep only j > r
            int shift = r - j0;
            unsigned dm = (shift < 0) ? ~0u : ((shift >= 31) ? 0u : (~0u << (shift + 1)));
            acc &= dm;
        }
        u.nms.masks32[r * MW + s] = acc;
    }
    __syncthreads();
    if (wave != 0) return;

    // phase 3: wave-0 greedy resolve (upper-triangle semantics)
    const unsigned long long below = (lane == 0) ? 0ull : (~0ull >> (64 - lane));
    unsigned long long S[MCH];
    #pragma unroll
    for (int w = 0; w < MCH; ++w) S[w] = 0ull;
    int nk = 0;
    bool done = false, allfull = true;

    #pragma unroll
    for (int c = 0; c < MCH; ++c) {
        if (done) break;
        unsigned long long vw = validw[c];
        unsigned long long eligible = vw & ~S[c];
        const int rbase = (c * 64 + lane) * MW;
        // in-chunk upper mask for row (c*64+lane): bits j>r within chunk
        unsigned long long Mu =
            ((unsigned long long)u.nms.masks32[rbase + 2 * c + 1] << 32) |
            (unsigned long long)u.nms.masks32[rbase + 2 * c];
        bool elig = (eligible >> lane) & 1ull;
        if (eligible) {
            int cap = MAXDET - nk;
            unsigned long long edge =
                __ballot(elig && ((Mu & eligible) != 0ull));  // elig r suppresses later elig
            unsigned long long keptm;
            if (edge == 0ull) {
                int rank = __popcll(eligible & below);
                keptm = __ballot(elig && (rank < cap));
            } else {
                unsigned long long km = 0ull, supm = 0ull;
                int cnt = 0;
                for (int m = 0; m < 64 && cnt < cap; ++m) {
                    if (!((eligible >> m) & 1ull)) continue;
                    if ((supm >> m) & 1ull) continue;
                    km |= 1ull << m;
                    ++cnt;
                    supm |= __shfl(Mu, m);
                }
                keptm = km;
            }
            if ((keptm >> lane) & 1ull) {
                int pos = nk + __popcll(keptm & below);
                int i = c * 64 + lane;
                float4 bb = sbox[i];
                u.nms.kb[pos] = u.nms.cbx[i];
                float* row = ob + pos * 6;
                row[0] = bb.x; row[1] = bb.y; row[2] = bb.z; row[3] = bb.w;
                row[4] = sscore[i]; row[5] = scls[i];
            }
            nk += __popcll(keptm);
            if (nk >= MAXDET) {
                done = true;
            } else if (keptm) {
                for (int w = c + 1; w < MCH; ++w) {
                    unsigned long long v = ((keptm >> lane) & 1ull)
                        ? (((unsigned long long)u.nms.masks32[rbase + 2 * w + 1] << 32) |
                           (unsigned long long)u.nms.masks32[rbase + 2 * w])
                        : 0ull;
                    v |= __shfl_xor(v, 1);  v |= __shfl_xor(v, 2);
                    v |= __shfl_xor(v, 4);  v |= __shfl_xor(v, 8);
                    v |= __shfl_xor(v, 16); v |= __shfl_xor(v, 32);
                    S[w] |= v;
                }
            }
        }
        if (vw != ~0ull) { allfull = false; break; }
    }

    // phase 4: exact fallback beyond MASKN (rarely taken)
    if (!done && allfull && nk < MAXDET) {
        const float4* BB4 = reinterpret_cast<const float4*>(cbox + (size_t)b * TOPKK * 4);
        const float* SS = cscore + (size_t)b * TOPKK;
        const float* CC = ccls + (size_t)b * TOPKK;
        __threadfence_block();
        for (int c = MCH; c < TOPKK / 64; ++c) {
            int i = c * 64 + lane;
            float sc = SS[i];
            bool valid = sc > CONF_T;
            unsigned long long validmask = __ballot(valid);
            if (validmask == 0ull) break;

            float cl = CC[i];
            float4 bb = BB4[i];
            float off = __fmul_rn(cl, CLS_OFF);
            float x1 = __fadd_rn(bb.x, off), y1 = __fadd_rn(bb.y, off);
            float x2 = __fadd_rn(bb.z, off), y2 = __fadd_rn(bb.w, off);
            float areaA = __fmul_rn(__fsub_rn(x2, x1), __fsub_rn(y2, y1));

            bool sup = false;
            for (int j = 0; j < nk; ++j) {
                float4 k4 = u.nms.kb[j];
                float lx = fmaxf(x1, k4.x), ly = fmaxf(y1, k4.y);
                float rx = fminf(x2, k4.z), ry = fminf(y2, k4.w);
                float iw = fmaxf(__fsub_rn(rx, lx), 0.0f);
                float ih = fmaxf(__fsub_rn(ry, ly), 0.0f);
                float inter = __fmul_rn(iw, ih);
                float areaB = __fmul_rn(__fsub_rn(k4.z, k4.x), __fsub_rn(k4.w, k4.y));
                float denom = __fadd_rn(__fsub_rn(__fadd_rn(areaA, areaB), inter), 1e-9f);
                if (inter > __fmul_rn(IOU_T, denom)) sup = true;
            }
            unsigned long long supprev = __ballot(sup);

            unsigned sb_lo = 0u, sb_hi = 0u;
            for (int m = 0; m < 64; ++m) {
                float mx1 = __shfl(x1, m), my1 = __shfl(y1, m);
                float mx2 = __shfl(x2, m), my2 = __shfl(y2, m);
                float lx = fmaxf(x1, mx1), ly = fmaxf(y1, my1);
                float rx = fminf(x2, mx2), ry = fminf(y2, my2);
                float iw = fmaxf(__fsub_rn(rx, lx), 0.0f);
                float ih = fmaxf(__fsub_rn(ry, ly), 0.0f);
                float inter = __fmul_rn(iw, ih);
                float areaB = __fmul_rn(__fsub_rn(mx2, mx1), __fsub_rn(my2, my1));
                float denom = __fadd_rn(__fsub_rn(__fadd_rn(areaA, areaB), inter), 1e-9f);
                bool s = (m != lane) && (inter > __fmul_rn(IOU_T, denom));
                if (m < 32) sb_lo |= ((unsigned)s) << m;
                else        sb_hi |= ((unsigned)s) << (m - 32);
            }

            unsigned long long eligible = validmask & ~supprev;
            unsigned long long mysb =
                (((unsigned long long)sb_hi << 32) | (unsigned long long)sb_lo);
            bool iselig = (eligible >> lane) & 1ull;
            unsigned long long edgeball =
                __ballot(iselig && ((mysb & eligible & below) != 0ull));

            unsigned long long keptm;
            int cap = MAXDET - nk;
            if (edgeball == 0ull) {
                int rank = __popcll(eligible & below);
                keptm = __ballot(iselig && (rank < cap));
            } else {
                unsigned long long km = 0ull;
                int cnt = 0;
                for (int m = 0; m < 64 && cnt < cap; ++m) {
                    if (!((validmask >> m) & 1ull)) break;
                    if ((supprev >> m) & 1ull) continue;
                    unsigned mlo = (unsigned)__shfl((int)sb_lo, m);
                    unsigned mhi = (unsigned)__shfl((int)sb_hi, m);
                    unsigned long long supby =
                        (((unsigned long long)mhi << 32) | (unsigned long long)mlo);
                    if (supby & km) continue;
                    km |= 1ull << m;
                    ++cnt;
                }
                keptm = km;
            }

            if ((keptm >> lane) & 1ull) {
                int pos = nk + __popcll(keptm & below);
                u.nms.kb[pos] = make_float4(x1, y1, x2, y2);
                float* row = ob + pos * 6;
                row[0] = bb.x; row[1] = bb.y; row[2] = bb.z; row[3] = bb.w;
                row[4] = sc;   row[5] = cl;
            }
            __threadfence_block();
            nk += __popcll(keptm);
            if (nk >= MAXDET) break;
            if (validmask != ~0ull) break;
        }
    }

    for (int x = nk * 6 + lane; x < MAXDET * 6; x += 64) ob[x] = 0.0f;
}

extern "C" void kernel_launch(void* const* d_in, const int* in_sizes, int n_in,
                              void* d_out, int out_size, void* d_ws, size_t ws_size,
                              hipStream_t stream) {
    const float* preds = (const float*)d_in[0];
    float* out = (float*)d_out;

    unsigned long long* keys = (unsigned long long*)d_ws;
    unsigned char* cls8 = (unsigned char*)(keys + (size_t)BATCH * NPRED);
    size_t off = (size_t)BATCH * NPRED * 8 + (size_t)BATCH * NPRED; // 16-aligned
    float* cbox = (float*)((char*)d_ws + off);
    float* cscore = cbox + (size_t)BATCH * TOPKK * 4;
    float* ccls = cscore + (size_t)BATCH * TOPKK;

    hipLaunchKernelGGL(k_score, dim3(BATCH * NPRED / 64), dim3(64), 0, stream,
                       preds, keys, cls8);
    hipLaunchKernelGGL(k_fused, dim3(BATCH), dim3(1024), 0, stream,
                       preds, keys, cls8, cbox, cscore, ccls, out);
}